// Round 1
// baseline (78.178 us; speedup 1.0000x reference)
//
#include <hip/hip_runtime.h>
#include <math.h>

#define NQ 9
#define NREPS 2
#define NB 512            // 2^NQ amplitudes
#define NSIMS (16*28*28)  // 12544  (= 49 * 256 exactly)

// ---------------- compile-time GF(2) linear algebra of the CNOT ring ----------------
// sigma = source-index permutation of the composed CNOT ring (linear over GF(2)).
__host__ __device__ constexpr int csigma(int b) {
    for (int c = NQ - 1; c >= 0; --c) {
        const int t  = (c + 1) % NQ;
        const int pc = NQ - 1 - c;
        const int pt = NQ - 1 - t;
        b ^= ((b >> pc) & 1) << pt;
    }
    return b;
}
__host__ __device__ constexpr int csig2(int b) { return csigma(csigma(b)); }

// Qubit i is measured along b-bit position Pi = 8-i.
__host__ __device__ constexpr int PIOF(int i)  { return NQ - 1 - i; }
// V_i = sigma^2(e_Pi): v-bit positions where the pair (b, b^m_i) has flipped factors.
__host__ __device__ constexpr int VMASK(int i) { return csig2(1 << PIOF(i)); }
__host__ __device__ constexpr int SCOMP(int i) { return (~VMASK(i)) & ((1 << NQ) - 1); }
__host__ __device__ constexpr int NV(int i)    { int m = SCOMP(i), c = 0; while (m) { c += m & 1; m >>= 1; } return c; }
__host__ __device__ constexpr int CBASE(int i) { int s = 0; for (int k = 0; k < i; ++k) s += 1 << NV(k); return s; }
// t-th set bit position (LSB-first) of SCOMP(i)
__host__ __device__ constexpr int POSI(int i, int t) {
    int m = SCOMP(i), p = 0;
    while (true) { if (m & 1) { if (t == 0) return p; --t; } m >>= 1; ++p; }
}

// column k of sigma^2 as a bitmask over output bit positions
__device__ const int d_COL[NQ] = {
    csig2(1 << 0), csig2(1 << 1), csig2(1 << 2), csig2(1 << 3), csig2(1 << 4),
    csig2(1 << 5), csig2(1 << 6), csig2(1 << 7), csig2(1 << 8)
};

// ---------------- multilinear Horner evaluation over LDS coefficients ----------------
// heval<L>(cf, vx) = sum_{u < 2^L} cf[u] * prod_{t: bit_t(u)} vx[t]
template<int L>
__device__ __forceinline__ float heval(const float* __restrict__ cf, const float* vx) {
    if constexpr (L == 2) {
        const float4 g = *reinterpret_cast<const float4*>(cf);   // 16B-aligned, uniform addr -> broadcast
        return (g.x + vx[0] * g.y) + vx[1] * (g.z + vx[0] * g.w);
    } else {
        return heval<L - 1>(cf, vx) + vx[L - 1] * heval<L - 1>(cf + (1 << (L - 1)), vx);
    }
}

template<int I>
__device__ __forceinline__ float qubit_eval(const float* __restrict__ coefI,
                                            const float* ca, const float* sa) {
    constexpr int V = NV(I);
    float vx[7];
    if constexpr (V > 0) vx[0] = ca[NQ - 1 - POSI(I, 0)];
    if constexpr (V > 1) vx[1] = ca[NQ - 1 - POSI(I, 1)];
    if constexpr (V > 2) vx[2] = ca[NQ - 1 - POSI(I, 2)];
    if constexpr (V > 3) vx[3] = ca[NQ - 1 - POSI(I, 3)];
    if constexpr (V > 4) vx[4] = ca[NQ - 1 - POSI(I, 4)];
    if constexpr (V > 5) vx[5] = ca[NQ - 1 - POSI(I, 5)];
    if constexpr (V > 6) vx[6] = ca[NQ - 1 - POSI(I, 6)];
    const float g = heval<V>(coefI, vx);
    // prefactor: prod over j in S_i of sin(a_{8-j})  (full angles)
    float sp = 1.f;
    if constexpr ((VMASK(I) & (1 << 0)) != 0) sp *= sa[8];
    if constexpr ((VMASK(I) & (1 << 1)) != 0) sp *= sa[7];
    if constexpr ((VMASK(I) & (1 << 2)) != 0) sp *= sa[6];
    if constexpr ((VMASK(I) & (1 << 3)) != 0) sp *= sa[5];
    if constexpr ((VMASK(I) & (1 << 4)) != 0) sp *= sa[4];
    if constexpr ((VMASK(I) & (1 << 5)) != 0) sp *= sa[3];
    if constexpr ((VMASK(I) & (1 << 6)) != 0) sp *= sa[2];
    if constexpr ((VMASK(I) & (1 << 7)) != 0) sp *= sa[1];
    if constexpr ((VMASK(I) & (1 << 8)) != 0) sp *= sa[0];
    return sp * g;
}

// ---------------- single fused kernel ----------------
// Phase 1-4 (per block, redundant, weights-only): build the 1024 Walsh coefficients in LDS.
//   e_i = SP_i * sum_{J subset S_i^c} (prod cos) * W_i[J],
//   W_i[J] = 2^-8 * sum_{b: bit_Pi=0} sin(Theta(b|m)-Theta(b)) * (-1)^<sigma2^T J, b>
// Phase 5: one simulation per lane, 9 Horner trees, no cross-lane traffic.
__global__ __launch_bounds__(256) void quanv_fused(
    const float* __restrict__ x,    // [16][28][28]
    const float* __restrict__ w,    // [NREPS][NQ]
    float* __restrict__ out)        // [16][9][28][28]
{
    __shared__ float sTc[NB], sTs[NB];
    __shared__ float sD[NQ][256];
    __shared__ __align__(16) float sCoef[1024];
    const int tid = threadIdx.x;

    // --- Phase 1: Theta(b) phase table (identical math to the verified setup kernel) ---
    for (int b = tid; b < NB; b += 256) {
        float th = 0.f;
        int cur = b;
        #pragma unroll
        for (int l = NREPS - 1; l >= 0; --l) {
            cur = csigma(cur);
            #pragma unroll
            for (int q = 0; q < NQ; ++q) {
                const float wq = 0.5f * w[l * NQ + q];
                th += ((cur >> (NQ - 1 - q)) & 1) ? wq : -wq;
            }
        }
        th -= 1.5707963267948966f * (float)__popc((unsigned)cur);
        float s, c;
        sincosf(th, &s, &c);
        sTc[b] = c; sTs[b] = s;
    }
    __syncthreads();

    // --- Phase 2: D_i(y) = sin(Theta(b|m_i) - Theta(b)), y = b with bit Pi dropped ---
    for (int idx = tid; idx < NQ * 256; idx += 256) {
        const int i  = idx >> 8, y = idx & 255;
        const int Pi = NQ - 1 - i;
        const int b  = ((y >> Pi) << (Pi + 1)) | (y & ((1 << Pi) - 1));
        const int b2 = b | (1 << Pi);
        sD[i][y] = sTs[b2] * sTc[b] - sTc[b2] * sTs[b];
    }
    __syncthreads();

    // --- Phase 3: in-place 256-point Walsh-Hadamard transform per qubit ---
    for (int s = 0; s < 8; ++s) {
        for (int idx = tid; idx < NQ * 128; idx += 256) {
            const int i  = idx >> 7, k = idx & 127;
            const int y0 = ((k >> s) << (s + 1)) | (k & ((1 << s) - 1));
            const int y1 = y0 | (1 << s);
            const float a = sD[i][y0], bb = sD[i][y1];
            sD[i][y0] = a + bb;
            sD[i][y1] = a - bb;
        }
        __syncthreads();
    }

    // --- Phase 4: gather coefficients into Horner consumption order ---
    for (int idx = tid; idx < 1024; idx += 256) {
        int i, u;
        if (idx < 896)      { i = idx >> 7; u = idx & 127; }
        else if (idx < 960) { i = 7; u = idx - 896; }
        else                { i = 8; u = idx - 960; }
        const int Pi = NQ - 1 - i;
        // J = deposit bits of u into SCOMP(i) (LSB-first); VMASK(i) == d_COL[Pi]
        int sc = (~d_COL[Pi]) & ((1 << NQ) - 1);
        int J = 0, uu = u;
        while (sc) { const int low = sc & (-sc); if (uu & 1) J |= low; sc &= sc - 1; uu >>= 1; }
        // MJ = sigma2^T(J): bit k = parity(col_k & J)
        int MJ = 0;
        #pragma unroll
        for (int k = 0; k < NQ; ++k) MJ |= (__popc((unsigned)(d_COL[k] & J)) & 1) << k;
        const int w8 = ((MJ >> (Pi + 1)) << Pi) | (MJ & ((1 << Pi) - 1));  // drop bit Pi
        sCoef[idx] = sD[i][w8] * (1.0f / 256.0f);   // folds the 2 * 2^-9 prefactor
    }
    __syncthreads();

    // --- Phase 5: one simulation per lane ---
    const int sim = blockIdx.x * 256 + tid;     // grid is exact: 49*256 == 12544
    const int ox  = sim % 28;
    const int t1  = sim / 28;
    const int oy  = t1 % 28;
    const int img = t1 / 28;

    float ca[NQ], sa[NQ];                        // FULL-angle cos/sin of the 9 patch pixels
    #pragma unroll
    for (int q = 0; q < NQ; ++q) {
        const int ky = q / 3, kx = q % 3;
        const int yy = oy + ky - 1, xx = ox + kx - 1;
        float a = 0.f;
        if (yy >= 0 && yy < 28 && xx >= 0 && xx < 28)
            a = x[img * 784 + yy * 28 + xx];
        __sincosf(a, &sa[q], &ca[q]);
    }

    float* o = out + img * (NQ * 784) + oy * 28 + ox;
    o[0 * 784] = qubit_eval<0>(sCoef + CBASE(0), ca, sa);
    o[1 * 784] = qubit_eval<1>(sCoef + CBASE(1), ca, sa);
    o[2 * 784] = qubit_eval<2>(sCoef + CBASE(2), ca, sa);
    o[3 * 784] = qubit_eval<3>(sCoef + CBASE(3), ca, sa);
    o[4 * 784] = qubit_eval<4>(sCoef + CBASE(4), ca, sa);
    o[5 * 784] = qubit_eval<5>(sCoef + CBASE(5), ca, sa);
    o[6 * 784] = qubit_eval<6>(sCoef + CBASE(6), ca, sa);
    o[7 * 784] = qubit_eval<7>(sCoef + CBASE(7), ca, sa);
    o[8 * 784] = qubit_eval<8>(sCoef + CBASE(8), ca, sa);
}

extern "C" void kernel_launch(void* const* d_in, const int* in_sizes, int n_in,
                              void* d_out, int out_size, void* d_ws, size_t ws_size,
                              hipStream_t stream) {
    const float* x = (const float*)d_in[0];   // 16*1*28*28 fp32
    const float* w = (const float*)d_in[1];   // NREPS*NQ fp32
    float* out = (float*)d_out;               // 16*9*28*28 fp32
    (void)d_ws; (void)ws_size; (void)in_sizes; (void)n_in; (void)out_size;

    quanv_fused<<<NSIMS / 256, 256, 0, stream>>>(x, w, out);
}

// Round 2
// 60.514 us; speedup vs baseline: 1.2919x; 1.2919x over previous
//
#include <hip/hip_runtime.h>
#include <math.h>

#define NQ 9
#define NREPS 2
#define NB 512            // 2^NQ amplitudes
#define NSIMS (16*28*28)  // 12544  (= 49 * 256 exactly)

// ---------------- compile-time GF(2) linear algebra of the CNOT ring ----------------
// sigma = source-index permutation of the composed CNOT ring (linear over GF(2)).
__host__ __device__ constexpr int csigma(int b) {
    for (int c = NQ - 1; c >= 0; --c) {
        const int t  = (c + 1) % NQ;
        const int pc = NQ - 1 - c;
        const int pt = NQ - 1 - t;
        b ^= ((b >> pc) & 1) << pt;
    }
    return b;
}
__host__ __device__ constexpr int csig2(int b) { return csigma(csigma(b)); }

// Qubit i is measured along b-bit position Pi = 8-i.
__host__ __device__ constexpr int PIOF(int i)  { return NQ - 1 - i; }
// V_i = sigma^2(e_Pi): v-bit positions where the pair (b, b^m_i) has flipped factors.
__host__ __device__ constexpr int VMASK(int i) { return csig2(1 << PIOF(i)); }
__host__ __device__ constexpr int SCOMP(int i) { return (~VMASK(i)) & ((1 << NQ) - 1); }
__host__ __device__ constexpr int NV(int i)    { int m = SCOMP(i), c = 0; while (m) { c += m & 1; m >>= 1; } return c; }
// t-th set bit position (LSB-first) of SCOMP(i)
__host__ __device__ constexpr int POSI(int i, int t) {
    int m = SCOMP(i), p = 0;
    while (true) { if (m & 1) { if (t == 0) return p; --t; } m >>= 1; ++p; }
}

// columns of sigma^2 (compile-time constants)
constexpr int COLC[NQ] = {
    csig2(1 << 0), csig2(1 << 1), csig2(1 << 2), csig2(1 << 3), csig2(1 << 4),
    csig2(1 << 5), csig2(1 << 6), csig2(1 << 7), csig2(1 << 8)
};

// ---------------- multilinear Horner evaluation over LDS coefficients ----------------
// heval<L>(cf, vx) = sum_{u < 2^L} cf[u] * prod_{t: bit_t(u)} vx[t]
template<int L>
__device__ __forceinline__ float heval(const float* __restrict__ cf, const float* vx) {
    if constexpr (L == 2) {
        const float4 g = *reinterpret_cast<const float4*>(cf);   // 16B-aligned, uniform addr -> broadcast
        return (g.x + vx[0] * g.y) + vx[1] * (g.z + vx[0] * g.w);
    } else {
        return heval<L - 1>(cf, vx) + vx[L - 1] * heval<L - 1>(cf + (1 << (L - 1)), vx);
    }
}

template<int I>
__device__ __forceinline__ float qubit_eval(const float* __restrict__ coefI,
                                            const float* ca, const float* sa) {
    constexpr int V = NV(I);
    float vx[7];
    if constexpr (V > 0) vx[0] = ca[NQ - 1 - POSI(I, 0)];
    if constexpr (V > 1) vx[1] = ca[NQ - 1 - POSI(I, 1)];
    if constexpr (V > 2) vx[2] = ca[NQ - 1 - POSI(I, 2)];
    if constexpr (V > 3) vx[3] = ca[NQ - 1 - POSI(I, 3)];
    if constexpr (V > 4) vx[4] = ca[NQ - 1 - POSI(I, 4)];
    if constexpr (V > 5) vx[5] = ca[NQ - 1 - POSI(I, 5)];
    if constexpr (V > 6) vx[6] = ca[NQ - 1 - POSI(I, 6)];
    const float g = heval<V>(coefI, vx);
    // prefactor: prod over j in S_i of sin(a_{8-j})  (full angles)
    float sp = 1.f;
    if constexpr ((VMASK(I) & (1 << 0)) != 0) sp *= sa[8];
    if constexpr ((VMASK(I) & (1 << 1)) != 0) sp *= sa[7];
    if constexpr ((VMASK(I) & (1 << 2)) != 0) sp *= sa[6];
    if constexpr ((VMASK(I) & (1 << 3)) != 0) sp *= sa[5];
    if constexpr ((VMASK(I) & (1 << 4)) != 0) sp *= sa[4];
    if constexpr ((VMASK(I) & (1 << 5)) != 0) sp *= sa[3];
    if constexpr ((VMASK(I) & (1 << 6)) != 0) sp *= sa[2];
    if constexpr ((VMASK(I) & (1 << 7)) != 0) sp *= sa[1];
    if constexpr ((VMASK(I) & (1 << 8)) != 0) sp *= sa[0];
    return sp * g;
}

// ---------------- per-qubit block body: phases 2-5 for qubit I ----------------
template<int I>
__device__ __forceinline__ void qubit_block(
    const float* __restrict__ x, float* __restrict__ out,
    const float* sTc, const float* sTs, float* sD, float* sCoef,
    const int tid, const int bx)
{
    constexpr int Pi  = NQ - 1 - I;
    constexpr int NVI = NV(I);

    // --- Phase 2: D(y) = sin(Theta(b|m_I) - Theta(b)), y = b with bit Pi dropped ---
    {
        const int y  = tid;                       // 256 entries, 1 per thread
        const int b  = ((y >> Pi) << (Pi + 1)) | (y & ((1 << Pi) - 1));
        const int b2 = b | (1 << Pi);
        sD[y] = sTs[b2] * sTc[b] - sTc[b2] * sTs[b];
    }
    __syncthreads();

    // --- Phase 3: in-place 256-point Walsh-Hadamard transform ---
    #pragma unroll
    for (int s = 0; s < 8; ++s) {
        if (tid < 128) {
            const int k  = tid;
            const int y0 = ((k >> s) << (s + 1)) | (k & ((1 << s) - 1));
            const int y1 = y0 | (1 << s);
            const float a = sD[y0], bb = sD[y1];
            sD[y0] = a + bb;
            sD[y1] = a - bb;
        }
        __syncthreads();
    }

    // --- Phase 4: gather coefficients into Horner consumption order ---
    if (tid < (1 << NVI)) {
        const int u = tid;
        // J = deposit bits of u into SCOMP(I) (LSB-first)
        int sc = SCOMP(I), J = 0, uu = u;
        while (sc) { const int low = sc & (-sc); if (uu & 1) J |= low; sc &= sc - 1; uu >>= 1; }
        // MJ = sigma2^T(J): bit k = parity(col_k & J)
        int MJ = 0;
        #pragma unroll
        for (int k = 0; k < NQ; ++k) MJ |= (__popc((unsigned)(COLC[k] & J)) & 1) << k;
        const int w8 = ((MJ >> (Pi + 1)) << Pi) | (MJ & ((1 << Pi) - 1));  // drop bit Pi
        sCoef[u] = sD[w8] * (1.0f / 256.0f);   // folds the 2 * 2^-9 prefactor
    }
    __syncthreads();

    // --- Phase 5: one simulation per thread, one qubit per block ---
    const int sim = bx * 256 + tid;               // grid.x is exact: 49*256 == 12544
    const int ox  = sim % 28;
    const int t1  = sim / 28;
    const int oy  = t1 % 28;
    const int img = t1 / 28;

    float ca[NQ], sa[NQ];                         // FULL-angle cos/sin of the 9 patch pixels
    #pragma unroll
    for (int q = 0; q < NQ; ++q) {
        const int ky = q / 3, kx = q % 3;
        const int yy = oy + ky - 1, xx = ox + kx - 1;
        float a = 0.f;
        if (yy >= 0 && yy < 28 && xx >= 0 && xx < 28)
            a = x[img * 784 + yy * 28 + xx];
        __sincosf(a, &sa[q], &ca[q]);
    }

    out[img * (NQ * 784) + I * 784 + oy * 28 + ox] = qubit_eval<I>(sCoef, ca, sa);
}

// ---------------- single fused kernel: grid (49, 9), blockIdx.y = qubit ----------------
__global__ __launch_bounds__(256) void quanv_fused(
    const float* __restrict__ x,    // [16][28][28]
    const float* __restrict__ w,    // [NREPS][NQ]
    float* __restrict__ out)        // [16][9][28][28]
{
    __shared__ float sTc[NB], sTs[NB];
    __shared__ float sD[256];
    __shared__ __align__(16) float sCoef[128];
    const int tid = threadIdx.x;

    // --- Phase 1: Theta(b) phase table (identical math to the verified version) ---
    #pragma unroll
    for (int b0 = 0; b0 < NB; b0 += 256) {
        const int b = b0 + tid;
        float th = 0.f;
        int cur = b;
        #pragma unroll
        for (int l = NREPS - 1; l >= 0; --l) {
            cur = csigma(cur);
            #pragma unroll
            for (int q = 0; q < NQ; ++q) {
                const float wq = 0.5f * w[l * NQ + q];
                th += ((cur >> (NQ - 1 - q)) & 1) ? wq : -wq;
            }
        }
        th -= 1.5707963267948966f * (float)__popc((unsigned)cur);
        float s, c;
        sincosf(th, &s, &c);
        sTc[b] = c; sTs[b] = s;
    }
    __syncthreads();

    switch (blockIdx.y) {
        case 0: qubit_block<0>(x, out, sTc, sTs, sD, sCoef, tid, blockIdx.x); break;
        case 1: qubit_block<1>(x, out, sTc, sTs, sD, sCoef, tid, blockIdx.x); break;
        case 2: qubit_block<2>(x, out, sTc, sTs, sD, sCoef, tid, blockIdx.x); break;
        case 3: qubit_block<3>(x, out, sTc, sTs, sD, sCoef, tid, blockIdx.x); break;
        case 4: qubit_block<4>(x, out, sTc, sTs, sD, sCoef, tid, blockIdx.x); break;
        case 5: qubit_block<5>(x, out, sTc, sTs, sD, sCoef, tid, blockIdx.x); break;
        case 6: qubit_block<6>(x, out, sTc, sTs, sD, sCoef, tid, blockIdx.x); break;
        case 7: qubit_block<7>(x, out, sTc, sTs, sD, sCoef, tid, blockIdx.x); break;
        case 8: qubit_block<8>(x, out, sTc, sTs, sD, sCoef, tid, blockIdx.x); break;
    }
}

extern "C" void kernel_launch(void* const* d_in, const int* in_sizes, int n_in,
                              void* d_out, int out_size, void* d_ws, size_t ws_size,
                              hipStream_t stream) {
    const float* x = (const float*)d_in[0];   // 16*1*28*28 fp32
    const float* w = (const float*)d_in[1];   // NREPS*NQ fp32
    float* out = (float*)d_out;               // 16*9*28*28 fp32
    (void)d_ws; (void)ws_size; (void)in_sizes; (void)n_in; (void)out_size;

    quanv_fused<<<dim3(NSIMS / 256, NQ), 256, 0, stream>>>(x, w, out);
}